// Round 1
// baseline (1275.174 us; speedup 1.0000x reference)
//
#include <hip/hip_runtime.h>
#include <cstddef>

#define B      64
#define IC     1152
#define CH     512
#define SPLITS 16     // i-splits for passA; IC/SPLITS = 72

// ---------------- reduction helpers ----------------

__device__ __forceinline__ float waveReduceSum(float v) {
    #pragma unroll
    for (int o = 32; o; o >>= 1) v += __shfl_down(v, o, 64);
    return v;
}
__device__ __forceinline__ float waveReduceMax(float v) {
    #pragma unroll
    for (int o = 32; o; o >>= 1) v = fmaxf(v, __shfl_down(v, o, 64));
    return v;
}

template<int NT>
__device__ __forceinline__ float blockReduceSum(float v, float* red) {
    __syncthreads();
    const int lane = threadIdx.x & 63, w = threadIdx.x >> 6;
    v = waveReduceSum(v);
    if (lane == 0) red[w] = v;
    __syncthreads();
    if (threadIdx.x == 0) {
        float t = red[0];
        #pragma unroll
        for (int k = 1; k < NT / 64; ++k) t += red[k];
        red[0] = t;
    }
    __syncthreads();
    return red[0];
}

template<int NT>
__device__ __forceinline__ float blockReduceMax(float v, float* red) {
    __syncthreads();
    const int lane = threadIdx.x & 63, w = threadIdx.x >> 6;
    v = waveReduceMax(v);
    if (lane == 0) red[w] = v;
    __syncthreads();
    if (threadIdx.x == 0) {
        float t = red[0];
        #pragma unroll
        for (int k = 1; k < NT / 64; ++k) t = fmaxf(t, red[k]);
        red[0] = t;
    }
    __syncthreads();
    return red[0];
}

// ---------------- setup kernels ----------------

// WT[j][c] = W[c][j]
__global__ __launch_bounds__(1024) void k_transpose(const float* __restrict__ W,
                                                    float* __restrict__ WT) {
    __shared__ float tile[32][33];
    int x = blockIdx.x * 32 + threadIdx.x;   // j
    int y = blockIdx.y * 32 + threadIdx.y;   // c
    tile[threadIdx.y][threadIdx.x] = W[(size_t)y * CH + x];
    __syncthreads();
    int tx = blockIdx.y * 32 + threadIdx.x;  // c
    int ty = blockIdx.x * 32 + threadIdx.y;  // j
    WT[(size_t)ty * CH + tx] = tile[threadIdx.x][threadIdx.y];
}

// WWT[a][c'] = sum_j W[a,j] * W[c',j]   (2 rows per block)
__global__ __launch_bounds__(256) void k_wwt(const float* __restrict__ W,
                                             const float* __restrict__ WT,
                                             float* __restrict__ WWT) {
    __shared__ float wa[2][CH];
    const int a0 = blockIdx.x * 2;
    for (int j = threadIdx.x; j < CH; j += 256) {
        wa[0][j] = W[(size_t)a0 * CH + j];
        wa[1][j] = W[(size_t)(a0 + 1) * CH + j];
    }
    __syncthreads();
    const int c0 = threadIdx.x, c1 = threadIdx.x + 256;
    float a00 = 0, a01 = 0, a10 = 0, a11 = 0;
    for (int j = 0; j < CH; ++j) {
        float w0 = wa[0][j], w1 = wa[1][j];
        float t0 = WT[(size_t)j * CH + c0], t1 = WT[(size_t)j * CH + c1];
        a00 += w0 * t0; a01 += w0 * t1;
        a10 += w1 * t0; a11 += w1 * t1;
    }
    WWT[(size_t)a0 * CH + c0] = a00;
    WWT[(size_t)a0 * CH + c1] = a01;
    WWT[(size_t)(a0 + 1) * CH + c0] = a10;
    WWT[(size_t)(a0 + 1) * CH + c1] = a11;
}

// Wb[c] = sum_j W[c,j]*bias[j] ;  bb = ||bias||^2
__global__ __launch_bounds__(512) void k_wb(const float* __restrict__ WT,
                                            const float* __restrict__ bias,
                                            float* __restrict__ Wb,
                                            float* __restrict__ bb) {
    __shared__ float bS[CH];
    __shared__ float red[8];
    const int c = threadIdx.x;
    bS[c] = bias[c];
    __syncthreads();
    float acc = 0;
    for (int j = 0; j < CH; ++j) acc += bS[j] * WT[(size_t)j * CH + c];
    Wb[c] = acc;
    float n2 = blockReduceSum<512>(bS[c] * bS[c], red);
    if (c == 0) *bb = n2;
}

__global__ void k_init(const float* __restrict__ coeffs, float* __restrict__ cvec) {
    int i = blockIdx.x * 256 + threadIdx.x;
    if (i < IC) cvec[i] = coeffs[i];
}

// ---------------- per-iteration kernels ----------------

// passA (+fused softmax): xcpart[is][b][c] = (1/Z) * sum_{i in split} exp(c_i - M) * x[b,i,c]
__global__ __launch_bounds__(256) void k_passA(const float* __restrict__ x,
                                               const float* __restrict__ cvec,
                                               float* __restrict__ xcpart) {
    __shared__ float eS[IC];
    __shared__ float red[4];
    const int b = blockIdx.x, is = blockIdx.y;
    const int t = threadIdx.x;

    // block-local softmax over all IC entries (redundant per block; cheap)
    float cl[5];
    float m = -3.4e38f;
    #pragma unroll
    for (int k = 0; k < 5; ++k) {
        int i = t + k * 256;
        cl[k] = (i < IC) ? cvec[i] : -3.4e38f;
        m = fmaxf(m, cl[k]);
    }
    float M = blockReduceMax<256>(m, red);
    float z = 0;
    #pragma unroll
    for (int k = 0; k < 5; ++k) {
        int i = t + k * 256;
        if (i < IC) { float e = expf(cl[k] - M); eS[i] = e; z += e; }
    }
    float Z = blockReduceSum<256>(z, red);
    const float invZ = 1.0f / Z;

    // weighted sum over this block's i-slice, float2 per thread
    const int i0 = is * (IC / SPLITS);
    float2 acc = make_float2(0.f, 0.f);
    const float2* xp = reinterpret_cast<const float2*>(x + ((size_t)b * IC + i0) * CH) + t;
    #pragma unroll 4
    for (int i = i0; i < i0 + IC / SPLITS; ++i) {
        float w = eS[i];
        float2 xv = *xp;
        acc.x += w * xv.x;
        acc.y += w * xv.y;
        xp += CH / 2;
    }
    float2* outp = reinterpret_cast<float2*>(xcpart + ((size_t)(is * B + b)) * CH) + t;
    *outp = make_float2(acc.x * invZ, acc.y * invZ);
}

// core: reduce xcpart -> xc_b ; h = WWT*xc ; n2 = xc.h + 2 Wb.xc + bb ; Wv = g*(h+Wb)
__global__ __launch_bounds__(1024) void k_core(const float* __restrict__ xcpart,
                                               const float* __restrict__ WWT,
                                               const float* __restrict__ Wb,
                                               const float* __restrict__ bbp,
                                               float* __restrict__ Wv) {
    __shared__ float xcS[CH];
    __shared__ float hS[CH];
    __shared__ float red[16];
    __shared__ float gS;
    const int b = blockIdx.x, tid = threadIdx.x;
    const int c = tid & (CH - 1), half = tid >> 9;

    if (half == 0) {
        float s = 0;
        #pragma unroll
        for (int is = 0; is < SPLITS; ++is) s += xcpart[((size_t)(is * B + b)) * CH + c];
        xcS[c] = s;
    }
    __syncthreads();

    float acc = 0;
    const int cp0 = half * (CH / 2);
    for (int cp = cp0; cp < cp0 + CH / 2; ++cp)
        acc += xcS[cp] * WWT[(size_t)cp * CH + c];
    if (half == 0) hS[c] = acc;
    __syncthreads();
    if (half == 1) hS[c] += acc;
    __syncthreads();

    float part = 0;
    if (half == 0) {
        float xcv = xcS[c];
        part = xcv * hS[c] + 2.0f * Wb[c] * xcv;
    }
    float tot = blockReduceSum<1024>(part, red);
    if (tid == 0) {
        float n2 = tot + *bbp;
        float n = sqrtf(n2);
        gS = n / (1.0f + n2);
    }
    __syncthreads();
    if (half == 0) Wv[(size_t)b * CH + c] = gS * (hS[c] + Wb[c]);
}

// passC: c[i] += sum_{b,c} x[b,i,c] * Wv[b,c]
__global__ __launch_bounds__(256) void k_passC(const float* __restrict__ x,
                                               const float* __restrict__ Wv,
                                               float* __restrict__ cvec) {
    __shared__ float red[4];
    const int i = blockIdx.x, t = threadIdx.x;
    float acc = 0;
    const float2* wvp = reinterpret_cast<const float2*>(Wv) + t;
    const float2* xp = reinterpret_cast<const float2*>(x) + (size_t)i * (CH / 2) + t;
    #pragma unroll 4
    for (int b = 0; b < B; ++b) {
        float2 xv = xp[(size_t)b * IC * (CH / 2)];
        float2 wv = wvp[(size_t)b * (CH / 2)];
        acc += xv.x * wv.x + xv.y * wv.y;
    }
    float tot = blockReduceSum<256>(acc, red);
    if (t == 0) cvec[i] += tot;
}

// final: s = xc.W + bias ; out = s * ||s||/(1+||s||^2)
__global__ __launch_bounds__(512) void k_final(const float* __restrict__ xcpart,
                                               const float* __restrict__ W,
                                               const float* __restrict__ bias,
                                               float* __restrict__ out) {
    __shared__ float xcS[CH];
    __shared__ float red[8];
    __shared__ float gS;
    const int b = blockIdx.x, j = threadIdx.x;
    float s = 0;
    #pragma unroll
    for (int is = 0; is < SPLITS; ++is) s += xcpart[((size_t)(is * B + b)) * CH + j];
    xcS[j] = s;
    __syncthreads();
    float sj = bias[j];
    for (int c = 0; c < CH; ++c) sj += xcS[c] * W[(size_t)c * CH + j];
    float n2 = blockReduceSum<512>(sj * sj, red);
    if (j == 0) { float n = sqrtf(n2); gS = n / (1.0f + n2); }
    __syncthreads();
    out[(size_t)b * CH + j] = sj * gS;
}

// ---------------- launch ----------------

extern "C" void kernel_launch(void* const* d_in, const int* in_sizes, int n_in,
                              void* d_out, int out_size, void* d_ws, size_t ws_size,
                              hipStream_t stream) {
    (void)in_sizes; (void)n_in; (void)out_size; (void)ws_size;
    const float* x      = (const float*)d_in[0];   // [64,1152,512]
    const float* W      = (const float*)d_in[1];   // [512,512]  (in,out)
    const float* bias   = (const float*)d_in[2];   // [512]
    const float* coeffs = (const float*)d_in[3];   // [1,1152,1]
    float* out = (float*)d_out;
    float* ws  = (float*)d_ws;

    float* WT     = ws;              // 262144
    float* WWT    = ws + 262144;     // 262144
    float* Wb     = ws + 524288;     // 512
    float* bb     = ws + 524800;     // 16 (scalar + pad)
    float* cvec   = ws + 524816;     // 1152
    float* Wv     = ws + 525968;     // 32768
    float* xcpart = ws + 558736;     // SPLITS*B*CH = 524288
    // total = 1083024 floats ~= 4.34 MB

    k_transpose<<<dim3(16, 16), dim3(32, 32), 0, stream>>>(W, WT);
    k_wwt<<<256, 256, 0, stream>>>(W, WT, WWT);
    k_wb<<<1, 512, 0, stream>>>(WT, bias, Wb, bb);
    k_init<<<5, 256, 0, stream>>>(coeffs, cvec);

    for (int t = 0; t < 9; ++t) {
        k_passA<<<dim3(B, SPLITS), 256, 0, stream>>>(x, cvec, xcpart);
        k_core<<<B, 1024, 0, stream>>>(xcpart, WWT, Wb, bb, Wv);
        k_passC<<<IC, 256, 0, stream>>>(x, Wv, cvec);
    }
    k_passA<<<dim3(B, SPLITS), 256, 0, stream>>>(x, cvec, xcpart);
    k_final<<<B, 512, 0, stream>>>(xcpart, W, bias, out);
}

// Round 10
// 1117.399 us; speedup vs baseline: 1.1412x; 1.1412x over previous
//
#include <hip/hip_runtime.h>
#include <cstddef>

#define B      64
#define IC     1152
#define CH     512
#define SPLITS 16     // i-splits for passA; IC/SPLITS = 72

// ---------------- helpers ----------------

__device__ __forceinline__ float waveReduceSum(float v) {
    #pragma unroll
    for (int o = 32; o; o >>= 1) v += __shfl_down(v, o, 64);
    return v;
}
__device__ __forceinline__ float waveReduceMax(float v) {
    #pragma unroll
    for (int o = 32; o; o >>= 1) v = fmaxf(v, __shfl_down(v, o, 64));
    return v;
}

template<int NT>
__device__ __forceinline__ float blockReduceSum(float v, float* red) {
    __syncthreads();
    const int lane = threadIdx.x & 63, w = threadIdx.x >> 6;
    v = waveReduceSum(v);
    if (lane == 0) red[w] = v;
    __syncthreads();
    if (threadIdx.x == 0) {
        float t = red[0];
        #pragma unroll
        for (int k = 1; k < NT / 64; ++k) t += red[k];
        red[0] = t;
    }
    __syncthreads();
    return red[0];
}

template<int NT>
__device__ __forceinline__ float blockReduceMax(float v, float* red) {
    __syncthreads();
    const int lane = threadIdx.x & 63, w = threadIdx.x >> 6;
    v = waveReduceMax(v);
    if (lane == 0) red[w] = v;
    __syncthreads();
    if (threadIdx.x == 0) {
        float t = red[0];
        #pragma unroll
        for (int k = 1; k < NT / 64; ++k) t = fmaxf(t, red[k]);
        red[0] = t;
    }
    __syncthreads();
    return red[0];
}

// bf16 pack (RNE) of two floats -> one uint (elem0 in low 16)
__device__ __forceinline__ unsigned bfpack2(float a, float b) {
    unsigned ua = __float_as_uint(a), ub = __float_as_uint(b);
    ua = (ua + 0x7FFFu + ((ua >> 16) & 1u)) >> 16;
    ub = (ub + 0x7FFFu + ((ub >> 16) & 1u)) & 0xFFFF0000u;
    return ua | ub;
}
// unpack one uint -> two floats
__device__ __forceinline__ void bfunpack2(unsigned u, float& lo, float& hi) {
    lo = __uint_as_float(u << 16);
    hi = __uint_as_float(u & 0xFFFF0000u);
}

// ---------------- setup kernels ----------------

// convert x (fp32) -> xbf (bf16), 8 elems/thread
__global__ __launch_bounds__(1024) void k_cvt(const float* __restrict__ x,
                                              uint4* __restrict__ xbf) {
    const size_t idx = (size_t)blockIdx.x * 1024 + threadIdx.x;  // uint4 index
    const float4* xp = reinterpret_cast<const float4*>(x) + idx * 2;
    float4 a = xp[0], b = xp[1];
    uint4 o;
    o.x = bfpack2(a.x, a.y);
    o.y = bfpack2(a.z, a.w);
    o.z = bfpack2(b.x, b.y);
    o.w = bfpack2(b.z, b.w);
    xbf[idx] = o;
}

// WT[j][c] = W[c][j]
__global__ __launch_bounds__(1024) void k_transpose(const float* __restrict__ W,
                                                    float* __restrict__ WT) {
    __shared__ float tile[32][33];
    int x = blockIdx.x * 32 + threadIdx.x;   // j
    int y = blockIdx.y * 32 + threadIdx.y;   // c
    tile[threadIdx.y][threadIdx.x] = W[(size_t)y * CH + x];
    __syncthreads();
    int tx = blockIdx.y * 32 + threadIdx.x;  // c
    int ty = blockIdx.x * 32 + threadIdx.y;  // j
    WT[(size_t)ty * CH + tx] = tile[threadIdx.x][threadIdx.y];
}

// WWT[a][c'] = sum_j W[a,j] * W[c',j]
__global__ __launch_bounds__(256) void k_wwt(const float* __restrict__ W,
                                             const float* __restrict__ WT,
                                             float* __restrict__ WWT) {
    __shared__ float wa[2][CH];
    const int a0 = blockIdx.x * 2;
    for (int j = threadIdx.x; j < CH; j += 256) {
        wa[0][j] = W[(size_t)a0 * CH + j];
        wa[1][j] = W[(size_t)(a0 + 1) * CH + j];
    }
    __syncthreads();
    const int c0 = threadIdx.x, c1 = threadIdx.x + 256;
    float a00 = 0, a01 = 0, a10 = 0, a11 = 0;
    for (int j = 0; j < CH; ++j) {
        float w0 = wa[0][j], w1 = wa[1][j];
        float t0 = WT[(size_t)j * CH + c0], t1 = WT[(size_t)j * CH + c1];
        a00 += w0 * t0; a01 += w0 * t1;
        a10 += w1 * t0; a11 += w1 * t1;
    }
    WWT[(size_t)a0 * CH + c0] = a00;
    WWT[(size_t)a0 * CH + c1] = a01;
    WWT[(size_t)(a0 + 1) * CH + c0] = a10;
    WWT[(size_t)(a0 + 1) * CH + c1] = a11;
}

// Wb[c] = sum_j W[c,j]*bias[j] ;  bb = ||bias||^2
__global__ __launch_bounds__(512) void k_wb(const float* __restrict__ WT,
                                            const float* __restrict__ bias,
                                            float* __restrict__ Wb,
                                            float* __restrict__ bb) {
    __shared__ float bS[CH];
    __shared__ float red[8];
    const int c = threadIdx.x;
    bS[c] = bias[c];
    __syncthreads();
    float acc = 0;
    for (int j = 0; j < CH; ++j) acc += bS[j] * WT[(size_t)j * CH + c];
    Wb[c] = acc;
    float n2 = blockReduceSum<512>(bS[c] * bS[c], red);
    if (c == 0) *bb = n2;
}

__global__ void k_init(const float* __restrict__ coeffs, float* __restrict__ cvec) {
    int i = blockIdx.x * 256 + threadIdx.x;
    if (i < IC) cvec[i] = coeffs[i];
}

// ---------------- per-iteration kernels (bf16 fast path) ----------------

// passA (+fused softmax): xcpart[is][b][c] = (1/Z)*sum_{i in slice} e_i * x[b,i,c]
// 256 threads: 4 row-parities x 64 col-threads (8 bf16 = 16B per thread per row)
__global__ __launch_bounds__(256) void k_passA(const uint4* __restrict__ xbf,
                                               const float* __restrict__ cvec,
                                               float* __restrict__ xcpart) {
    __shared__ float eS[IC];
    __shared__ float accS[3][CH];
    __shared__ float red[4];
    const int b = blockIdx.x, is = blockIdx.y;
    const int t = threadIdx.x;

    // block-local softmax over IC entries (redundant per block; cheap)
    float cl[5];
    float m = -3.4e38f;
    #pragma unroll
    for (int k = 0; k < 5; ++k) {
        int i = t + k * 256;
        cl[k] = (i < IC) ? cvec[i] : -3.4e38f;
        m = fmaxf(m, cl[k]);
    }
    float M = blockReduceMax<256>(m, red);
    float z = 0;
    #pragma unroll
    for (int k = 0; k < 5; ++k) {
        int i = t + k * 256;
        if (i < IC) { float e = expf(cl[k] - M); eS[i] = e; z += e; }
    }
    float Z = blockReduceSum<256>(z, red);
    const float invZ = 1.0f / Z;

    const int rp = t >> 6;        // row parity 0..3
    const int c8 = t & 63;        // 8-float column group
    const int i0 = is * (IC / SPLITS);

    float acc[8];
    #pragma unroll
    for (int e = 0; e < 8; ++e) acc[e] = 0.f;

    const uint4* xp = xbf + ((size_t)(b * IC + i0 + rp) * (CH / 8)) + c8;
    #pragma unroll 2
    for (int k = 0; k < IC / SPLITS / 4; ++k) {
        float w = eS[i0 + rp + 4 * k];
        uint4 u = xp[(size_t)k * 4 * (CH / 8)];
        float f0, f1;
        bfunpack2(u.x, f0, f1); acc[0] += w * f0; acc[1] += w * f1;
        bfunpack2(u.y, f0, f1); acc[2] += w * f0; acc[3] += w * f1;
        bfunpack2(u.z, f0, f1); acc[4] += w * f0; acc[5] += w * f1;
        bfunpack2(u.w, f0, f1); acc[6] += w * f0; acc[7] += w * f1;
    }
    if (rp > 0) {
        #pragma unroll
        for (int e = 0; e < 8; ++e) accS[rp - 1][c8 * 8 + e] = acc[e];
    }
    __syncthreads();
    if (rp == 0) {
        float4 o0, o1;
        #pragma unroll
        for (int e = 0; e < 8; ++e) {
            float v = acc[e] + accS[0][c8 * 8 + e] + accS[1][c8 * 8 + e] + accS[2][c8 * 8 + e];
            if (e < 4) reinterpret_cast<float*>(&o0)[e] = v * invZ;
            else       reinterpret_cast<float*>(&o1)[e - 4] = v * invZ;
        }
        float4* outp = reinterpret_cast<float4*>(xcpart + ((size_t)(is * B + b)) * CH) + c8 * 2;
        outp[0] = o0;
        outp[1] = o1;
    }
}

// core: reduce xcpart -> xc_b ; h = WWT*xc ; n2 = xc.h + 2 Wb.xc + bb ; Wv = g*(h+Wb)
__global__ __launch_bounds__(1024) void k_core(const float* __restrict__ xcpart,
                                               const float* __restrict__ WWT,
                                               const float* __restrict__ Wb,
                                               const float* __restrict__ bbp,
                                               float* __restrict__ Wv) {
    __shared__ float xcS[CH];
    __shared__ float hS[CH];
    __shared__ float red[16];
    __shared__ float gS;
    const int b = blockIdx.x, tid = threadIdx.x;
    const int c = tid & (CH - 1), half = tid >> 9;

    if (half == 0) {
        float s = 0;
        #pragma unroll
        for (int is = 0; is < SPLITS; ++is) s += xcpart[((size_t)(is * B + b)) * CH + c];
        xcS[c] = s;
    }
    __syncthreads();

    float acc = 0;
    const int cp0 = half * (CH / 2);
    for (int cp = cp0; cp < cp0 + CH / 2; ++cp)
        acc += xcS[cp] * WWT[(size_t)cp * CH + c];
    if (half == 0) hS[c] = acc;
    __syncthreads();
    if (half == 1) hS[c] += acc;
    __syncthreads();

    float part = 0;
    if (half == 0) {
        float xcv = xcS[c];
        part = xcv * hS[c] + 2.0f * Wb[c] * xcv;
    }
    float tot = blockReduceSum<1024>(part, red);
    if (tid == 0) {
        float n2 = tot + *bbp;
        float n = sqrtf(n2);
        gS = n / (1.0f + n2);
    }
    __syncthreads();
    if (half == 0) Wv[(size_t)b * CH + c] = gS * (hS[c] + Wb[c]);
}

// passC: c[i] += sum_{b,c} x[b,i,c] * Wv[b,c]
__global__ __launch_bounds__(256) void k_passC(const uint4* __restrict__ xbf,
                                               const float* __restrict__ Wv,
                                               float* __restrict__ cvec) {
    __shared__ float red[4];
    const int i = blockIdx.x, t = threadIdx.x;
    const int bp = t >> 6;        // batch parity 0..3
    const int c8 = t & 63;

    float acc = 0;
    #pragma unroll 2
    for (int k = 0; k < B / 4; ++k) {
        int b = bp + 4 * k;
        uint4 u = xbf[((size_t)(b * IC + i)) * (CH / 8) + c8];
        const float4* wvp = reinterpret_cast<const float4*>(Wv + (size_t)b * CH) + c8 * 2;
        float4 w0 = wvp[0], w1 = wvp[1];
        float f0, f1;
        bfunpack2(u.x, f0, f1); acc += f0 * w0.x + f1 * w0.y;
        bfunpack2(u.y, f0, f1); acc += f0 * w0.z + f1 * w0.w;
        bfunpack2(u.z, f0, f1); acc += f0 * w1.x + f1 * w1.y;
        bfunpack2(u.w, f0, f1); acc += f0 * w1.z + f1 * w1.w;
    }
    float tot = blockReduceSum<256>(acc, red);
    if (t == 0) cvec[i] += tot;
}

// ---------------- fp32 fallback streaming kernels (round-1 validated) ----------------

__global__ __launch_bounds__(256) void k_passA_f32(const float* __restrict__ x,
                                                   const float* __restrict__ cvec,
                                                   float* __restrict__ xcpart) {
    __shared__ float eS[IC];
    __shared__ float red[4];
    const int b = blockIdx.x, is = blockIdx.y;
    const int t = threadIdx.x;

    float cl[5];
    float m = -3.4e38f;
    #pragma unroll
    for (int k = 0; k < 5; ++k) {
        int i = t + k * 256;
        cl[k] = (i < IC) ? cvec[i] : -3.4e38f;
        m = fmaxf(m, cl[k]);
    }
    float M = blockReduceMax<256>(m, red);
    float z = 0;
    #pragma unroll
    for (int k = 0; k < 5; ++k) {
        int i = t + k * 256;
        if (i < IC) { float e = expf(cl[k] - M); eS[i] = e; z += e; }
    }
    float Z = blockReduceSum<256>(z, red);
    const float invZ = 1.0f / Z;

    const int i0 = is * (IC / SPLITS);
    float2 acc = make_float2(0.f, 0.f);
    const float2* xp = reinterpret_cast<const float2*>(x + ((size_t)b * IC + i0) * CH) + t;
    #pragma unroll 4
    for (int i = i0; i < i0 + IC / SPLITS; ++i) {
        float w = eS[i];
        float2 xv = *xp;
        acc.x += w * xv.x;
        acc.y += w * xv.y;
        xp += CH / 2;
    }
    float2* outp = reinterpret_cast<float2*>(xcpart + ((size_t)(is * B + b)) * CH) + t;
    *outp = make_float2(acc.x * invZ, acc.y * invZ);
}

__global__ __launch_bounds__(256) void k_passC_f32(const float* __restrict__ x,
                                                   const float* __restrict__ Wv,
                                                   float* __restrict__ cvec) {
    __shared__ float red[4];
    const int i = blockIdx.x, t = threadIdx.x;
    float acc = 0;
    const float2* wvp = reinterpret_cast<const float2*>(Wv) + t;
    const float2* xp = reinterpret_cast<const float2*>(x) + (size_t)i * (CH / 2) + t;
    #pragma unroll 4
    for (int b = 0; b < B; ++b) {
        float2 xv = xp[(size_t)b * IC * (CH / 2)];
        float2 wv = wvp[(size_t)b * (CH / 2)];
        acc += xv.x * wv.x + xv.y * wv.y;
    }
    float tot = blockReduceSum<256>(acc, red);
    if (t == 0) cvec[i] += tot;
}

// final: s = xc.W + bias ; out = s * ||s||/(1+||s||^2)
__global__ __launch_bounds__(512) void k_final(const float* __restrict__ xcpart,
                                               const float* __restrict__ W,
                                               const float* __restrict__ bias,
                                               float* __restrict__ out) {
    __shared__ float xcS[CH];
    __shared__ float red[8];
    __shared__ float gS;
    const int b = blockIdx.x, j = threadIdx.x;
    float s = 0;
    #pragma unroll
    for (int is = 0; is < SPLITS; ++is) s += xcpart[((size_t)(is * B + b)) * CH + j];
    xcS[j] = s;
    __syncthreads();
    float sj = bias[j];
    for (int c = 0; c < CH; ++c) sj += xcS[c] * W[(size_t)c * CH + j];
    float n2 = blockReduceSum<512>(sj * sj, red);
    if (j == 0) { float n = sqrtf(n2); gS = n / (1.0f + n2); }
    __syncthreads();
    out[(size_t)b * CH + j] = sj * gS;
}

// ---------------- launch ----------------

extern "C" void kernel_launch(void* const* d_in, const int* in_sizes, int n_in,
                              void* d_out, int out_size, void* d_ws, size_t ws_size,
                              hipStream_t stream) {
    (void)in_sizes; (void)n_in; (void)out_size;
    const float* x      = (const float*)d_in[0];   // [64,1152,512]
    const float* W      = (const float*)d_in[1];   // [512,512]  (in,out)
    const float* bias   = (const float*)d_in[2];   // [512]
    const float* coeffs = (const float*)d_in[3];   // [1,1152,1]
    float* out = (float*)d_out;

    const size_t xbf_bytes  = (size_t)B * IC * CH * 2;        // 75.5 MB
    const size_t f32_floats = 1083024;                        // fp32 scratch block
    const bool fast = ws_size >= xbf_bytes + f32_floats * 4 + 256;

    uint4* xbf = (uint4*)d_ws;
    float* ws  = fast ? (float*)((char*)d_ws + xbf_bytes) : (float*)d_ws;

    float* WT     = ws;              // 262144
    float* WWT    = ws + 262144;     // 262144
    float* Wb     = ws + 524288;     // 512
    float* bb     = ws + 524800;     // 16
    float* cvec   = ws + 524816;     // 1152
    float* Wv     = ws + 525968;     // 32768
    float* xcpart = ws + 558736;     // SPLITS*B*CH = 524288

    if (fast)
        k_cvt<<<(B * IC * CH / 8) / 1024, 1024, 0, stream>>>(x, xbf);
    k_transpose<<<dim3(16, 16), dim3(32, 32), 0, stream>>>(W, WT);
    k_wwt<<<256, 256, 0, stream>>>(W, WT, WWT);
    k_wb<<<1, 512, 0, stream>>>(WT, bias, Wb, bb);
    k_init<<<5, 256, 0, stream>>>(coeffs, cvec);

    for (int t = 0; t < 9; ++t) {
        if (fast) {
            k_passA<<<dim3(B, SPLITS), 256, 0, stream>>>(xbf, cvec, xcpart);
            k_core<<<B, 1024, 0, stream>>>(xcpart, WWT, Wb, bb, Wv);
            k_passC<<<IC, 256, 0, stream>>>(xbf, Wv, cvec);
        } else {
            k_passA_f32<<<dim3(B, SPLITS), 256, 0, stream>>>(x, cvec, xcpart);
            k_core<<<B, 1024, 0, stream>>>(xcpart, WWT, Wb, bb, Wv);
            k_passC_f32<<<IC, 256, 0, stream>>>(x, Wv, cvec);
        }
    }
    if (fast)
        k_passA<<<dim3(B, SPLITS), 256, 0, stream>>>(xbf, cvec, xcpart);
    else
        k_passA_f32<<<dim3(B, SPLITS), 256, 0, stream>>>(x, cvec, xcpart);
    k_final<<<B, 512, 0, stream>>>(xcpart, W, bias, out);
}